// Round 1
// baseline (383.767 us; speedup 1.0000x reference)
//
#include <hip/hip_runtime.h>

#define B_ 64
#define C_ 1024
#define Q_ 128
#define H_ 256

typedef __attribute__((ext_vector_type(8))) short bfrag;   // 8 x bf16
typedef __attribute__((ext_vector_type(4))) float f32x4;

__device__ __forceinline__ short f2bf(float f) {
    union { float f; unsigned u; } v; v.f = f;
    unsigned u = v.u;
    unsigned r = u + 0x7fffu + ((u >> 16) & 1u);
    return (short)(r >> 16);
}
__device__ __forceinline__ float bf2f(short s) {
    union { float f; unsigned u; } v;
    v.u = ((unsigned)(unsigned short)s) << 16;
    return v.f;
}

// ---------------- K0: qdot[b,q] = query[b,q,:] . w_q + att_b ----------------
__global__ __launch_bounds__(256) void k_qdot(
    const float* __restrict__ qry, const float* __restrict__ attw,
    const float* __restrict__ attb, float* __restrict__ qdot)
{
    const int tid = threadIdx.x, lane = tid & 63, w = tid >> 6;
    const int bid = blockIdx.x;           // 0..2047
    const int b = bid >> 5, qg = bid & 31;
    const int q = qg * 4 + w;
    const float* src = qry + ((size_t)b * Q_ + q) * H_ + lane * 4;
    f32x4 v = *(const f32x4*)src;
    f32x4 wv = *(const f32x4*)(attw + H_ + lane * 4);   // w_q = att_w[H:2H]
    float p = v.x * wv.x + v.y * wv.y + v.z * wv.z + v.w * wv.w;
    #pragma unroll
    for (int d = 1; d < 64; d <<= 1) p += __shfl_xor(p, d);
    if (lane == 0) qdot[b * Q_ + q] = p + attb[0];
}

// ---------------- K1: sim -> softmax -> a ; writes out cols 0..2, smax -----
#define SPAD 40    // k-slice row stride (32 + 8 pad)
#define PPAD 136   // P row stride (128 + 8 pad)

__global__ __launch_bounds__(256) void k_sim(
    const float* __restrict__ ctx,   // [B,C,H]
    const float* __restrict__ qry,   // [B,Q,H]
    const float* __restrict__ attw,  // [3H]
    const float* __restrict__ qdot,  // ws [B,Q]
    float* __restrict__ smax,        // ws [B,C]
    float* __restrict__ out)         // [B,C,4H]
{
    __shared__ float wm_s[H_];
    __shared__ float wc_s[H_];
    __shared__ float qd_s[Q_];
    __shared__ float cdot_s[64];
    __shared__ short qh_s[Q_][SPAD];
    __shared__ short ql_s[Q_][SPAD];
    __shared__ short ch_s[64][SPAD];
    __shared__ short cl_s[64][SPAD];
    __shared__ short P_s[64][PPAD];

    const int tid = threadIdx.x;
    const int lane = tid & 63;
    const int w = tid >> 6;
    const int bid = blockIdx.x;
    const int b = bid >> 4;
    const int c0 = (bid & 15) * 64;

    // stage weights + qdot
    wc_s[tid] = attw[tid];            // w_c = att_w[0:H]
    wm_s[tid] = attw[2 * H_ + tid];   // w_m = att_w[2H:3H]
    if (tid < Q_) qd_s[tid] = qdot[b * Q_ + tid];
    __syncthreads();

    const int r16 = lane & 15;   // 0..15
    const int kp  = lane >> 4;   // 0..3

    f32x4 acc[8];
    #pragma unroll
    for (int t = 0; t < 8; ++t) acc[t] = (f32x4)(0.f);

    float cdp = 0.f;

    const int crow = tid >> 2;          // 0..63
    const int ckof = (tid & 3) * 8;     // 0,8,16,24
    const int qrow = tid >> 1;          // 0..127
    const int qkof = (tid & 1) * 16;    // 0,16

    const float* ctxb = ctx + ((size_t)b * C_ + c0) * H_;
    const float* qryb = qry + (size_t)b * Q_ * H_;

    for (int k0 = 0; k0 < H_; k0 += 32) {
        // ---- stage context slice (cm = ctx*w_m, hi/lo) + cdot partial ----
        {
            const float* src = ctxb + crow * H_ + k0 + ckof;
            f32x4 v0 = *(const f32x4*)(src);
            f32x4 v1 = *(const f32x4*)(src + 4);
            float tv[8];
            *(f32x4*)&tv[0] = v0;
            *(f32x4*)&tv[4] = v1;
            bfrag hv, lv;
            #pragma unroll
            for (int j = 0; j < 8; ++j) {
                int k = k0 + ckof + j;
                cdp += tv[j] * wc_s[k];
                float cm = tv[j] * wm_s[k];
                short hi = f2bf(cm);
                hv[j] = hi;
                lv[j] = f2bf(cm - bf2f(hi));
            }
            *(bfrag*)&ch_s[crow][ckof] = hv;
            *(bfrag*)&cl_s[crow][ckof] = lv;
        }
        // ---- stage query slice (hi/lo) ----
        {
            const float* src = qryb + qrow * H_ + k0 + qkof;
            f32x4 v0 = *(const f32x4*)(src);
            f32x4 v1 = *(const f32x4*)(src + 4);
            f32x4 v2 = *(const f32x4*)(src + 8);
            f32x4 v3 = *(const f32x4*)(src + 12);
            float tv[16];
            *(f32x4*)&tv[0]  = v0;
            *(f32x4*)&tv[4]  = v1;
            *(f32x4*)&tv[8]  = v2;
            *(f32x4*)&tv[12] = v3;
            bfrag h0v, l0v, h1v, l1v;
            #pragma unroll
            for (int j = 0; j < 8; ++j) {
                short hi = f2bf(tv[j]);
                h0v[j] = hi;
                l0v[j] = f2bf(tv[j] - bf2f(hi));
            }
            #pragma unroll
            for (int j = 0; j < 8; ++j) {
                short hi = f2bf(tv[8 + j]);
                h1v[j] = hi;
                l1v[j] = f2bf(tv[8 + j] - bf2f(hi));
            }
            *(bfrag*)&qh_s[qrow][qkof]     = h0v;
            *(bfrag*)&ql_s[qrow][qkof]     = l0v;
            *(bfrag*)&qh_s[qrow][qkof + 8] = h1v;
            *(bfrag*)&ql_s[qrow][qkof + 8] = l1v;
        }
        __syncthreads();
        // ---- MFMA: sim tiles (hi*hi + hi*lo + lo*hi) ----
        bfrag a_hi = *(bfrag*)&ch_s[w * 16 + r16][kp * 8];
        bfrag a_lo = *(bfrag*)&cl_s[w * 16 + r16][kp * 8];
        #pragma unroll
        for (int t = 0; t < 8; ++t) {
            bfrag b_hi = *(bfrag*)&qh_s[t * 16 + r16][kp * 8];
            bfrag b_lo = *(bfrag*)&ql_s[t * 16 + r16][kp * 8];
            acc[t] = __builtin_amdgcn_mfma_f32_16x16x32_bf16(a_hi, b_hi, acc[t], 0, 0, 0);
            acc[t] = __builtin_amdgcn_mfma_f32_16x16x32_bf16(a_lo, b_hi, acc[t], 0, 0, 0);
            acc[t] = __builtin_amdgcn_mfma_f32_16x16x32_bf16(a_hi, b_lo, acc[t], 0, 0, 0);
        }
        __syncthreads();
    }

    // ---- cdot reduce (4 staging threads per row) ----
    {
        float cv = cdp;
        cv += __shfl_xor(cv, 1);
        cv += __shfl_xor(cv, 2);
        if ((lane & 3) == 0) cdot_s[crow] = cv;
    }
    __syncthreads();

    // ---- softmax over q (rows: w*16 + kp*4 + r, cols: t*16 + r16) ----
    float qdv[8];
    #pragma unroll
    for (int t = 0; t < 8; ++t) qdv[t] = qd_s[t * 16 + r16];
    float cdv[4];
    #pragma unroll
    for (int r = 0; r < 4; ++r) cdv[r] = cdot_s[w * 16 + kp * 4 + r];

    #pragma unroll
    for (int r = 0; r < 4; ++r) {
        float ev[8];
        float m = -1e30f;
        #pragma unroll
        for (int t = 0; t < 8; ++t) {
            float s = acc[t][r] + cdv[r] + qdv[t];
            ev[t] = s;
            m = fmaxf(m, s);
        }
        m = fmaxf(m, __shfl_xor(m, 1));
        m = fmaxf(m, __shfl_xor(m, 2));
        m = fmaxf(m, __shfl_xor(m, 4));
        m = fmaxf(m, __shfl_xor(m, 8));
        float ssum = 0.f;
        #pragma unroll
        for (int t = 0; t < 8; ++t) {
            float e = __expf(ev[t] - m);
            ev[t] = e;
            ssum += e;
        }
        ssum += __shfl_xor(ssum, 1);
        ssum += __shfl_xor(ssum, 2);
        ssum += __shfl_xor(ssum, 4);
        ssum += __shfl_xor(ssum, 8);
        const int rr = w * 16 + kp * 4 + r;
        if (r16 == 0) smax[(size_t)b * C_ + c0 + rr] = m;
        float inv = 1.f / ssum;
        #pragma unroll
        for (int t = 0; t < 8; ++t)
            P_s[rr][t * 16 + r16] = f2bf(ev[t] * inv);
    }
    __syncthreads();

    // ---- a = P @ query : wave w owns h columns [w*64, w*64+64) ----
    f32x4 a2[4][4];
    #pragma unroll
    for (int m = 0; m < 4; ++m)
        #pragma unroll
        for (int i = 0; i < 4; ++i) a2[m][i] = (f32x4)(0.f);

    const int h0w = w * 64;
    for (int kq = 0; kq < 4; ++kq) {
        bfrag ap[4];
        #pragma unroll
        for (int m = 0; m < 4; ++m)
            ap[m] = *(bfrag*)&P_s[m * 16 + r16][kq * 32 + kp * 8];
        #pragma unroll
        for (int i = 0; i < 4; ++i) {
            const float* qc = qryb + (size_t)(kq * 32 + kp * 8) * H_ + h0w + i * 16 + r16;
            bfrag bq;
            #pragma unroll
            for (int j = 0; j < 8; ++j) bq[j] = f2bf(qc[(size_t)j * H_]);
            #pragma unroll
            for (int m = 0; m < 4; ++m)
                a2[m][i] = __builtin_amdgcn_mfma_f32_16x16x32_bf16(ap[m], bq, a2[m][i], 0, 0, 0);
        }
    }

    // ---- epilogue: out[:,0:H]=ctx, [H:2H]=a, [2H:3H]=ctx*a ----
    #pragma unroll
    for (int m = 0; m < 4; ++m) {
        #pragma unroll
        for (int r = 0; r < 4; ++r) {
            const int cl = m * 16 + kp * 4 + r;
            const size_t orow = ((size_t)b * C_ + c0 + cl) * (4 * H_);
            const float* crow_p = ctxb + (size_t)cl * H_;
            #pragma unroll
            for (int i = 0; i < 4; ++i) {
                const int h = h0w + i * 16 + r16;
                float av = a2[m][i][r];
                float cvx = crow_p[h];
                out[orow + h] = cvx;
                out[orow + H_ + h] = av;
                out[orow + 2 * H_ + h] = cvx * av;
            }
        }
    }
}

// ---------------- K2: beta softmax over C + partial b_vec -------------------
__global__ __launch_bounds__(256) void k_beta(
    const float* __restrict__ ctx, const float* __restrict__ smax,
    float* __restrict__ bpart)   // [B*4, H]
{
    __shared__ float beta_s[C_];
    __shared__ float red_s[8];
    const int tid = threadIdx.x, lane = tid & 63, w = tid >> 6;
    const int bid = blockIdx.x;      // 0..255
    const int b = bid >> 2, quad = bid & 3;

    f32x4 v = *(const f32x4*)(smax + (size_t)b * C_ + tid * 4);
    float m = fmaxf(fmaxf(v.x, v.y), fmaxf(v.z, v.w));
    #pragma unroll
    for (int d = 1; d < 64; d <<= 1) m = fmaxf(m, __shfl_xor(m, d));
    if (lane == 0) red_s[w] = m;
    __syncthreads();
    m = fmaxf(fmaxf(red_s[0], red_s[1]), fmaxf(red_s[2], red_s[3]));

    f32x4 e;
    e.x = __expf(v.x - m); e.y = __expf(v.y - m);
    e.z = __expf(v.z - m); e.w = __expf(v.w - m);
    float s = e.x + e.y + e.z + e.w;
    #pragma unroll
    for (int d = 1; d < 64; d <<= 1) s += __shfl_xor(s, d);
    if (lane == 0) red_s[4 + w] = s;
    __syncthreads();
    s = red_s[4] + red_s[5] + red_s[6] + red_s[7];
    float inv = 1.f / s;
    *(f32x4*)&beta_s[tid * 4] = e * inv;
    __syncthreads();

    // partial b_vec over rows [quad*256, quad*256+256), h = tid
    const float* cb = ctx + ((size_t)b * C_ + quad * 256) * H_ + tid;
    float acc = 0.f;
    #pragma unroll 8
    for (int i = 0; i < 256; ++i)
        acc += beta_s[quad * 256 + i] * cb[(size_t)i * H_];
    bpart[(size_t)bid * H_ + tid] = acc;
}

// ---------------- K3: out[:,3H:4H] = ctx * b_vec ---------------------------
__global__ __launch_bounds__(256) void k_colb(
    const float* __restrict__ ctx, const float* __restrict__ bpart,
    float* __restrict__ out)
{
    const int tid = threadIdx.x;
    const int bid = blockIdx.x;          // 0..16383
    const int b = bid >> 8, cg = bid & 255;
    const int c = cg * 4 + (tid >> 6);
    const int h = (tid & 63) * 4;

    const float* bp = bpart + (size_t)b * 4 * H_ + h;
    f32x4 bv = *(const f32x4*)bp;
    bv += *(const f32x4*)(bp + H_);
    bv += *(const f32x4*)(bp + 2 * H_);
    bv += *(const f32x4*)(bp + 3 * H_);

    const size_t rowi = (size_t)b * C_ + c;
    f32x4 cv = *(const f32x4*)(ctx + rowi * H_ + h);
    *(f32x4*)(out + rowi * (4 * H_) + 3 * H_ + h) = cv * bv;
}

extern "C" void kernel_launch(void* const* d_in, const int* in_sizes, int n_in,
                              void* d_out, int out_size, void* d_ws, size_t ws_size,
                              hipStream_t stream) {
    const float* ctx  = (const float*)d_in[0];
    const float* qry  = (const float*)d_in[2];
    const float* attw = (const float*)d_in[4];
    const float* attb = (const float*)d_in[5];
    float* out = (float*)d_out;

    float* qdot  = (float*)d_ws;          // B*Q
    float* smax  = qdot + B_ * Q_;        // B*C
    float* bpart = smax + B_ * C_;        // 256*H

    k_qdot<<<B_ * 32, 256, 0, stream>>>(qry, attw, attb, qdot);
    k_sim<<<B_ * 16, 256, 0, stream>>>(ctx, qry, attw, qdot, smax, out);
    k_beta<<<B_ * 4, 256, 0, stream>>>(ctx, smax, bpart);
    k_colb<<<B_ * 256, 256, 0, stream>>>(ctx, bpart, out);
}